// Round 10
// baseline (5381.017 us; speedup 1.0000x reference)
//
#include <hip/hip_runtime.h>
#include <cstddef>
#include <cstdint>

// CubicRNN MI355X — round 14: controlled split of r13's bundle.
// r13 (fast-math + vectorization together) regressed 78.8->93.6 us/dispatch
// with VALUBusy DOWN as predicted -> added stall, likely the quarter-rate
// long-latency trans-pipe dependency chain (6-deep, 1 output/thread/pass,
// no ILP between barriers). This round: r12 gating math restored EXACTLY
// (libcall expf/tanhf, bit-identical), keeping ONLY the phase-3/4 f32x4
// load vectorization with SERIAL accumulation in the original c2 order
// (bit-exact; absmax must return to 3.72529e-09 — built-in attribution
// check). Phase-3 LDS instrs /4 (64 b32 -> 16 b128 per thread).
// Structure frozen at r12: kg4 x n2 (B once/block [r10]), sequential z/x
// (r11), f16 exchange (r12), folded frame_fill (r12), diagonal z-batching,
// 2 blocks/CU. Geometry/streams frozen at r4 (r5/r6 lesson).
// B=4, T=10, C=1, H=W=64, HC=32, S=3, L=3, kx=3, kz=5, ky=1, 18 steps.

typedef __attribute__((ext_vector_type(8))) _Float16 f16x8;
typedef __attribute__((ext_vector_type(4))) _Float16 f16x4;
typedef __attribute__((ext_vector_type(4))) float f32x4;
typedef unsigned short u16;

#define HW 4096
#define NB 4

__device__ __forceinline__ float sigm(float x){ return 1.f/(1.f+expf(-x)); }
__device__ __forceinline__ u16 f2h(float x){
  _Float16 h = (_Float16)x;
  union { _Float16 f; u16 u; } c; c.f = h; return c.u;
}

__global__ __launch_bounds__(256) void zero4(uint4* __restrict__ p, size_t n){
  size_t i = (size_t)blockIdx.x*blockDim.x + threadIdx.x;
  size_t st = (size_t)gridDim.x*blockDim.x;
  uint4 z = make_uint4(0u,0u,0u,0u);
  for (; i < n; i += st) p[i] = z;
}

// Pack conv weights (fp32 OIHW) -> [unit=tap*3+kc][co(128)][k(32)] f16 single,
// cat channels remapped to uniform 96 (layer0: ci0->k0, ci1..64->k32..95).
__global__ __launch_bounds__(256) void pack_w(const float* __restrict__ src,
    u16* __restrict__ dst, int taps, int cin, int l0){
  int idx = blockIdx.x*256 + threadIdx.x;
  int k = idx & 31, co = (idx>>5) & 127, rest = idx >> 12;
  int tap = rest/3, kc = rest - tap*3;
  int p = kc*32 + k;
  int ci = l0 ? ((p==0) ? 0 : ((p>=32) ? p-31 : -1)) : p;
  float wv = 0.f;
  if (ci >= 0 && ci < cin) wv = src[((size_t)co*cin + ci)*taps + tap];
  dst[idx] = f2h(wv);
}

// cat layout: [b][chunk 0..23][pixel 0..4095][elem 0..7] f16; only chunks
// 0..11 (hi) are live. chunk = slot>>3, elem = slot&7 (slot 0..95).
// Chunks 12..23 are dead padding (address-geometry pinned to r4).
__device__ __forceinline__ void put_hi(u16* base, int b, int slot, int pix, float v){
  size_t o = ((size_t)(b*24 + (slot>>3))*4096 + pix)*8 + (slot&7);
  base[o] = f2h(v);
}

struct CellArgs {
  const u16* cat_in;                       // chunk-planar f16 (12 live chunks)
  const float* src0; int src0_bs;          // l0 frame source (null = use cat plane 0)
  const u16* wz; const u16* wx;            // packed f16 weights
  const float *bx, *bz;                    // [128]
  const float* cx_src; float* cx_dst;      // [B][4096][32] fp32 (dst may be null)
  float* cz;                               // in-place
  u16 *hx0, *hx1, *hz, *y_dst;             // cat base pointers (null = skip)
  const float *wy, *by;                    // [32][64],[32]
  const float *wl;                         // [32]; non-null = pred mode
  float *pred_out;                         // predbuf slot [B][4096]
  float *final_out;                        // d_out + ti*4096 (b-stride 40960) or null
};
struct MultiArgs { CellArgs c[3]; };

// LDS map:
//   halo  uint4 [0, 27840)       12 planes x 145
//   exch  f16x4 [27840, 44224)   2048 entries x 8B (kg4 x n2 x nf4 x 64 lanes)
//   hbufF f32   [44224, 61632)   [64px][68]
//   ybufF f32   [27840, 38080)   [64px][40] overlays exch (dead after x-reduce)
// 61,632 B; regs ~128 unified -> 2 blocks/CU, 4 waves/SIMD.
#define LDS_BYTES 61632

__global__ __launch_bounds__(512, 4) void cell_kernel(MultiArgs ma){
  __shared__ __align__(16) char smem[LDS_BYTES];
  uint4* AU4   = (uint4*)smem;
  f16x4* exch  = (f16x4*)(smem + 27840);
  float* hbufF = (float*)(smem + 44224);
  float* ybufF = (float*)(smem + 27840);

  const CellArgs a = ma.c[blockIdx.z];
  const int tid = threadIdx.x;
  const int b = blockIdx.y;
  const int reg = blockIdx.x;
  const int R0 = (reg >> 3) << 3, C0 = (reg & 7) << 3;   // 8x8 pixel region

  // ---- phase 0: stage 12x12 halo, 12 live chunk-planes, coalesced.
  //      l0 cells: plane 0 built from inseq/predbuf (frame_fill folded). ----
  for (int i = tid; i < 1728; i += 512) {
    int px = i % 144, cp = i / 144;
    int hr = px / 12, hc = px - hr*12;
    int gy = R0 + hr - 2, gx = C0 + hc - 2;
    bool inb = (gy >= 0 && gy < 64 && gx >= 0 && gx < 64);
    uint4 v = make_uint4(0u,0u,0u,0u);
    if (a.src0 && cp == 0) {
      if (inb) v.x = (unsigned)f2h(a.src0[(size_t)b*a.src0_bs + gy*64 + gx]);
    } else if (inb) {
      v = *reinterpret_cast<const uint4*>(a.cat_in + ((size_t)(b*24 + cp)*4096 + gy*64 + gx)*8);
    }
    AU4[cp*145 + px] = v;
  }
  __syncthreads();

  const int wave = tid >> 6, lane = tid & 63;
  const int n = wave & 1, kg = wave >> 1;        // kg 0..3 (B loaded once/block)
  const int q = lane >> 4, n16 = lane & 15;
  const int row_in = n16 >> 3, col = n16 & 7;
  const int wlo = (n*64 + n16)*32 + q*8;         // lane weight offset (nf adds 512)

  f32x4 zf = {0.f,0.f,0.f,0.f};
  f32x4 acc[4][4];                               // [nf][m]; reused z then x

  // ================= z branch =================
#pragma unroll
  for (int nf = 0; nf < 4; ++nf)
#pragma unroll
    for (int m = 0; m < 4; ++m) acc[nf][m] = zf;

#pragma unroll 1
  for (int u = kg; u < 75; u += 4) {
    int tap = u/3, kc = u - tap*3;
    int ky = tap/5, kx = tap - ky*5;

    f16x8 Bz[4];
#pragma unroll
    for (int nf = 0; nf < 4; ++nf)
      Bz[nf] = *(const f16x8*)(a.wz + (size_t)u*4096 + wlo + nf*512);

    int ai0 = (kc*4 + q)*145 + (row_in + ky)*12 + col + kx;
    f16x8 Ah[4];
#pragma unroll
    for (int m = 0; m < 4; ++m)
      Ah[m] = *(const f16x8*)(AU4 + ai0 + m*24);

#pragma unroll
    for (int nf = 0; nf < 4; ++nf)
#pragma unroll
      for (int m = 0; m < 4; ++m)
        acc[nf][m] = __builtin_amdgcn_mfma_f32_16x16x32_f16(Ah[m], Bz[nf], acc[nf][m], 0,0,0);
  }

  // z-reduce (4-way over kg, f16 exchange) + gating, 4 passes, 512 threads
#pragma unroll
  for (int m = 0; m < 4; ++m) {
    __syncthreads();                             // exch free (prev pass read)
#pragma unroll
    for (int nf = 0; nf < 4; ++nf)
      exch[((kg*2 + n)*4 + nf)*64 + lane] = __builtin_convertvector(acc[nf][m], f16x4);
    __syncthreads();
    {
      int ch = tid & 31, p16 = tid >> 5;         // 16 px x 32 ch
      float g4[4];
#pragma unroll
      for (int g = 0; g < 4; ++g) {
        int co = g*32 + ch;
        int nn = co >> 6, nf = (co >> 4) & 3, nl = co & 15;
        int qq = p16 >> 2;
        f32x4 s = zf;
#pragma unroll
        for (int kgg = 0; kgg < 4; ++kgg)
          s += __builtin_convertvector(exch[((kgg*2 + nn)*4 + nf)*64 + qq*16 + nl], f32x4);
        g4[g] = s[p16 & 3] + a.bz[co];
      }
      int px = (2*m + (p16 >> 3))*8 + (p16 & 7);
      int pxg = (R0 + (px >> 3))*64 + C0 + (px & 7);
      size_t pix = (size_t)b*4096 + pxg;
      float c = a.cz[pix*32 + ch];
      float cn = sigm(g4[1] + 0.01f)*c + sigm(g4[0])*tanhf(g4[2]);
      float h = sigm(g4[3])*tanhf(cn);
      a.cz[pix*32 + ch] = cn;
      if (a.hz) put_hi(a.hz, b, 64 + ch, pxg, h);
      hbufF[px*68 + 32 + ch] = h;
    }
  }

  // ================= x branch =================
#pragma unroll
  for (int nf = 0; nf < 4; ++nf)
#pragma unroll
    for (int m = 0; m < 4; ++m) acc[nf][m] = zf;

#pragma unroll 1
  for (int xi = kg; xi < 27; xi += 4) {          // halo still live (no overlay)
    int tap3 = xi/3, kc = xi - tap3*3;
    int ky = tap3/3 + 1, kx = tap3 - (ky-1)*3 + 1;

    f16x8 Bx[4];
#pragma unroll
    for (int nf = 0; nf < 4; ++nf)
      Bx[nf] = *(const f16x8*)(a.wx + (size_t)xi*4096 + wlo + nf*512);

    int ai0 = (kc*4 + q)*145 + (row_in + ky)*12 + col + kx;
    f16x8 Ah[4];
#pragma unroll
    for (int m = 0; m < 4; ++m)
      Ah[m] = *(const f16x8*)(AU4 + ai0 + m*24);

#pragma unroll
    for (int nf = 0; nf < 4; ++nf)
#pragma unroll
      for (int m = 0; m < 4; ++m)
        acc[nf][m] = __builtin_amdgcn_mfma_f32_16x16x32_f16(Ah[m], Bx[nf], acc[nf][m], 0,0,0);
  }

  // x-reduce (f16 exchange) + gating, 4 passes
#pragma unroll
  for (int m = 0; m < 4; ++m) {
    __syncthreads();
#pragma unroll
    for (int nf = 0; nf < 4; ++nf)
      exch[((kg*2 + n)*4 + nf)*64 + lane] = __builtin_convertvector(acc[nf][m], f16x4);
    __syncthreads();
    {
      int ch = tid & 31, p16 = tid >> 5;
      float g4[4];
#pragma unroll
      for (int g = 0; g < 4; ++g) {
        int co = g*32 + ch;
        int nn = co >> 6, nf = (co >> 4) & 3, nl = co & 15;
        int qq = p16 >> 2;
        f32x4 s = zf;
#pragma unroll
        for (int kgg = 0; kgg < 4; ++kgg)
          s += __builtin_convertvector(exch[((kgg*2 + nn)*4 + nf)*64 + qq*16 + nl], f32x4);
        g4[g] = s[p16 & 3] + a.bx[co];
      }
      int px = (2*m + (p16 >> 3))*8 + (p16 & 7);
      int pxg = (R0 + (px >> 3))*64 + C0 + (px & 7);
      size_t pix = (size_t)b*4096 + pxg;
      float c = a.cx_src[pix*32 + ch];
      float cn = sigm(g4[1] + 0.01f)*c + sigm(g4[0])*tanhf(g4[2]);
      float h = sigm(g4[3])*tanhf(cn);
      if (a.cx_dst) a.cx_dst[pix*32 + ch] = cn;
      if (a.hx0) put_hi(a.hx0, b, 32 + ch, pxg, h);
      if (a.hx1) put_hi(a.hx1, b, 32 + ch, pxg, h);
      hbufF[px*68 + ch] = h;
    }
  }
  __syncthreads();

  // ---- phase 3: fused 1x1 y-conv (64 -> 32), f32x4 loads, serial adds
  //      (accumulation order identical to r12 -> bit-exact) ----
  if (a.wy) {
#pragma unroll 1
    for (int it = 0; it < 4; ++it) {
      int idx = tid + it*512;
      int co2 = idx & 31, px = idx >> 5;
      int pxg = (R0 + (px >> 3))*64 + C0 + (px & 7);
      float acc2 = a.by[co2];
      const f32x4* hv = (const f32x4*)(hbufF + px*68);
      const f32x4* wv = (const f32x4*)(a.wy + co2*64);
#pragma unroll
      for (int c4 = 0; c4 < 16; ++c4) {
        f32x4 hh = hv[c4], ww = wv[c4];
        acc2 += ww[0]*hh[0];
        acc2 += ww[1]*hh[1];
        acc2 += ww[2]*hh[2];
        acc2 += ww[3]*hh[3];
      }
      if (a.y_dst) put_hi(a.y_dst, b, co2, pxg, acc2);
      if (a.wl) ybufF[px*40 + co2] = acc2;
    }
  }
  // ---- phase 4: fused pred-conv (32 -> 1), last cell only ----
  if (a.wl) {
    __syncthreads();
    if (tid < 64) {
      int px = tid;
      int pxg = (R0 + (px >> 3))*64 + C0 + (px & 7);
      const f32x4* yv = (const f32x4*)(ybufF + px*40);
      const f32x4* wv = (const f32x4*)a.wl;
      float p = 0.f;
#pragma unroll
      for (int c4 = 0; c4 < 8; ++c4) {
        f32x4 yy = yv[c4], ww = wv[c4];
        p += ww[0]*yy[0];
        p += ww[1]*yy[1];
        p += ww[2]*yy[2];
        p += ww[3]*yy[3];
      }
      a.pred_out[(size_t)b*4096 + pxg] = p;
      if (a.final_out) a.final_out[(size_t)b*40960 + pxg] = p;
    }
  }
}

extern "C" void kernel_launch(void* const* d_in, const int* in_sizes, int n_in,
                              void* d_out, int out_size, void* d_ws, size_t ws_size,
                              hipStream_t stream)
{
  const float* input_seq = (const float*)d_in[0];
  const float* w_x0 = (const float*)d_in[1];
  const float* b_x0 = (const float*)d_in[2];
  const float* w_z0 = (const float*)d_in[3];
  const float* b_z0 = (const float*)d_in[4];
  const float* w_y0 = (const float*)d_in[5];
  const float* b_y0 = (const float*)d_in[6];
  const float* w_x1 = (const float*)d_in[7];
  const float* b_x1 = (const float*)d_in[8];
  const float* w_z1 = (const float*)d_in[9];
  const float* b_z1 = (const float*)d_in[10];
  const float* w_y1 = (const float*)d_in[11];
  const float* b_y1 = (const float*)d_in[12];
  const float* w_last = (const float*)d_in[13];
  (void)in_sizes; (void)n_in; (void)out_size; (void)ws_size;

  uint8_t* wsb = (uint8_t*)d_ws;
  size_t off = 0;
  auto alloc = [&](size_t bytes) -> void* {
    void* p = wsb + off; off += (bytes + 255) & ~(size_t)255; return p;
  };

  const size_t CATB = (size_t)NB*24*4096*8*2;    // 6,291,456 B (geometry pinned; lo half dead)
  u16* cat[3][3][2];
  for (int l = 0; l < 3; ++l)
    for (int s = 0; s < 3; ++s) {
      cat[l][s][0] = (u16*)alloc(CATB);
      cat[l][s][1] = (s == 0) ? (u16*)alloc(CATB) : cat[l][s][0];
    }
  const size_t CB = (size_t)NB*HW*32*4;          // 2,097,152 B
  float* cx[3][2]; float* cz[3];
  for (int l = 0; l < 3; ++l) { cx[l][0] = (float*)alloc(CB); cx[l][1] = (float*)alloc(CB); }
  for (int l = 0; l < 3; ++l) cz[l] = (float*)alloc(CB);
  size_t zero_bytes = off;                       // cats + cx + cz

  u16 *wzb[9], *wxb[9];
  for (int c = 0; c < 9; ++c) {
    wzb[c] = (u16*)alloc(75*4096*2);             // 25 taps x 3 kc x 128 co x 32 k
    wxb[c] = (u16*)alloc(27*4096*2);             // 9 taps x 3 kc
  }
  float* predbuf = (float*)alloc((size_t)18*NB*HW*4);

  zero4<<<2048, 256, 0, stream>>>((uint4*)wsb, zero_bytes/16);

  for (int l = 0; l < 3; ++l)
    for (int s = 0; s < 3; ++s) {
      int cell = l*3 + s;
      const float *srcx, *srcz; int cin;
      if (l == 0) { srcx = w_x0 + (size_t)s*128*65*9;  srcz = w_z0 + (size_t)s*128*65*25;  cin = 65; }
      else { int li = (l-1)*3 + s;
             srcx = w_x1 + (size_t)li*128*96*9; srcz = w_z1 + (size_t)li*128*96*25; cin = 96; }
      pack_w<<<(75*4096)/256, 256, 0, stream>>>(srcz, wzb[cell], 25, cin, l==0);
      pack_w<<<(27*4096)/256, 256, 0, stream>>>(srcx, wxb[cell], 9, cin, l==0);
    }

  // diagonal wavefront: independent cell groups per step
  static const int diag[5][3] = { {0,-1,-1}, {1,3,-1}, {2,4,6}, {5,7,-1}, {8,-1,-1} };

  for (int step = 0; step < 18; ++step) {
    int par = step & 1, npar = par ^ 1;

    auto make_cell = [&](int l, int s) -> CellArgs {
      CellArgs A;
      A.cat_in = cat[l][s][(s==0) ? par : 0];
      A.src0 = nullptr; A.src0_bs = 0;
      if (l == 0) {
        int j = step + s;
        if (j < 10) { A.src0 = input_seq + (size_t)j*HW; A.src0_bs = 10*HW; }
        else        { A.src0 = predbuf + (size_t)(j-3)*NB*HW; A.src0_bs = HW; }
      }
      int cell = l*3 + s;
      A.wz = wzb[cell]; A.wx = wxb[cell];
      if (l == 0) { A.bx = b_x0 + s*128; A.bz = b_z0 + s*128; }
      else { int li = (l-1)*3 + s; A.bx = b_x1 + li*128; A.bz = b_z1 + li*128; }
      A.cx_src = (s == 2) ? cx[l][1] : cx[l][0];
      A.cx_dst = (s == 0) ? cx[l][0] : ((s == 1) ? cx[l][1] : nullptr);
      A.cz = cz[l];
      A.hx0 = (s == 0) ? cat[l][1][0] : ((s == 1) ? cat[l][2][0] : nullptr);
      A.hx1 = (s == 0) ? cat[l][0][npar] : nullptr;
      A.hz  = (s < 2) ? cat[l][s+1][0] : cat[l][0][npar];
      A.wy = nullptr; A.by = nullptr; A.y_dst = nullptr;
      A.wl = nullptr; A.pred_out = nullptr; A.final_out = nullptr;
      if (l < 2) {
        if (l == 0) { A.wy = w_y0 + (size_t)s*32*64; A.by = b_y0 + s*32; }
        else        { A.wy = w_y1 + (size_t)s*32*64; A.by = b_y1 + s*32; }
        A.y_dst = cat[l+1][s][(s==0) ? par : 0];
      } else if (s == 2) {
        A.wy = w_y1 + (size_t)5*32*64; A.by = b_y1 + 5*32;
        A.wl = w_last;
        A.pred_out = predbuf + (size_t)step*NB*HW;
        A.final_out = (step >= 8) ? ((float*)d_out + (size_t)(step-8)*HW) : nullptr;
      }
      return A;
    };

    for (int d = 0; d < 5; ++d) {
      MultiArgs M{};
      int k = 0;
      for (int j = 0; j < 3; ++j) {
        int cid = diag[d][j];
        if (cid < 0) break;
        M.c[k++] = make_cell(cid/3, cid%3);
      }
      cell_kernel<<<dim3(64, NB, k), 512, 0, stream>>>(M);
    }
  }
}

// Round 11
// 4136.713 us; speedup vs baseline: 1.3008x; 1.3008x over previous
//
#include <hip/hip_runtime.h>
#include <cstddef>
#include <cstdint>

// CubicRNN MI355X — round 15: merged reduce passes on the exact r12 base.
// r13/r14 attribution complete: the f32x4 phase-3/4 rewrite was the
// regression (+21us stall, VALU/MFMA busy-time unchanged); scalar phase 3/4
// restored permanently. This round's single change: per-branch K-reduce
// 4 passes -> 2 passes of 2 m-frags each (exch doubled to 32 KB, LDS 78 KB
// — r11 proved 2 blocks/CU at this size). Each thread computes 2 outputs
// per pass: 2 independent 6-deep transcendental chains interleave (ILP x2
// on the latency-exposed gating chain) and barriers drop 16 -> 8.
// Per-output arithmetic order identical to r12 -> absmax must be exactly
// 3.72529e-09 (built-in attribution check).
// Structure frozen: kg4 x n2 (B once/block [r10]), sequential z/x (r11),
// f16 exchange (r12), folded frame_fill (r12), diagonal z-batching,
// geometry/streams at r4 (r5/r6 lesson).
// B=4, T=10, C=1, H=W=64, HC=32, S=3, L=3, kx=3, kz=5, ky=1, 18 steps.

typedef __attribute__((ext_vector_type(8))) _Float16 f16x8;
typedef __attribute__((ext_vector_type(4))) _Float16 f16x4;
typedef __attribute__((ext_vector_type(4))) float f32x4;
typedef unsigned short u16;

#define HW 4096
#define NB 4

__device__ __forceinline__ float sigm(float x){ return 1.f/(1.f+expf(-x)); }
__device__ __forceinline__ u16 f2h(float x){
  _Float16 h = (_Float16)x;
  union { _Float16 f; u16 u; } c; c.f = h; return c.u;
}

__global__ __launch_bounds__(256) void zero4(uint4* __restrict__ p, size_t n){
  size_t i = (size_t)blockIdx.x*blockDim.x + threadIdx.x;
  size_t st = (size_t)gridDim.x*blockDim.x;
  uint4 z = make_uint4(0u,0u,0u,0u);
  for (; i < n; i += st) p[i] = z;
}

// Pack conv weights (fp32 OIHW) -> [unit=tap*3+kc][co(128)][k(32)] f16 single,
// cat channels remapped to uniform 96 (layer0: ci0->k0, ci1..64->k32..95).
__global__ __launch_bounds__(256) void pack_w(const float* __restrict__ src,
    u16* __restrict__ dst, int taps, int cin, int l0){
  int idx = blockIdx.x*256 + threadIdx.x;
  int k = idx & 31, co = (idx>>5) & 127, rest = idx >> 12;
  int tap = rest/3, kc = rest - tap*3;
  int p = kc*32 + k;
  int ci = l0 ? ((p==0) ? 0 : ((p>=32) ? p-31 : -1)) : p;
  float wv = 0.f;
  if (ci >= 0 && ci < cin) wv = src[((size_t)co*cin + ci)*taps + tap];
  dst[idx] = f2h(wv);
}

// cat layout: [b][chunk 0..23][pixel 0..4095][elem 0..7] f16; only chunks
// 0..11 (hi) are live. chunk = slot>>3, elem = slot&7 (slot 0..95).
// Chunks 12..23 are dead padding (address-geometry pinned to r4).
__device__ __forceinline__ void put_hi(u16* base, int b, int slot, int pix, float v){
  size_t o = ((size_t)(b*24 + (slot>>3))*4096 + pix)*8 + (slot&7);
  base[o] = f2h(v);
}

struct CellArgs {
  const u16* cat_in;                       // chunk-planar f16 (12 live chunks)
  const float* src0; int src0_bs;          // l0 frame source (null = use cat plane 0)
  const u16* wz; const u16* wx;            // packed f16 weights
  const float *bx, *bz;                    // [128]
  const float* cx_src; float* cx_dst;      // [B][4096][32] fp32 (dst may be null)
  float* cz;                               // in-place
  u16 *hx0, *hx1, *hz, *y_dst;             // cat base pointers (null = skip)
  const float *wy, *by;                    // [32][64],[32]
  const float *wl;                         // [32]; non-null = pred mode
  float *pred_out;                         // predbuf slot [B][4096]
  float *final_out;                        // d_out + ti*4096 (b-stride 40960) or null
};
struct MultiArgs { CellArgs c[3]; };

// LDS map:
//   halo  uint4 [0, 27840)       12 planes x 145
//   exch  f16x4 [27840, 60608)   4096 entries x 8B (2 m-frags x 8 waves x nf4 x 64)
//   hbufF f32   [60608, 78016)   [64px][68]
//   ybufF f32   [27840, 37312)   [64px][37] overlays exch (dead after x-reduce)
// 78,016 B; ~128 unified regs -> 2 blocks/CU, 4 waves/SIMD (r11-proven).
#define LDS_BYTES 78016

__global__ __launch_bounds__(512, 4) void cell_kernel(MultiArgs ma){
  __shared__ __align__(16) char smem[LDS_BYTES];
  uint4* AU4   = (uint4*)smem;
  f16x4* exch  = (f16x4*)(smem + 27840);
  float* hbufF = (float*)(smem + 60608);
  float* ybufF = (float*)(smem + 27840);

  const CellArgs a = ma.c[blockIdx.z];
  const int tid = threadIdx.x;
  const int b = blockIdx.y;
  const int reg = blockIdx.x;
  const int R0 = (reg >> 3) << 3, C0 = (reg & 7) << 3;   // 8x8 pixel region

  // ---- phase 0: stage 12x12 halo, 12 live chunk-planes, coalesced.
  //      l0 cells: plane 0 built from inseq/predbuf (frame_fill folded). ----
  for (int i = tid; i < 1728; i += 512) {
    int px = i % 144, cp = i / 144;
    int hr = px / 12, hc = px - hr*12;
    int gy = R0 + hr - 2, gx = C0 + hc - 2;
    bool inb = (gy >= 0 && gy < 64 && gx >= 0 && gx < 64);
    uint4 v = make_uint4(0u,0u,0u,0u);
    if (a.src0 && cp == 0) {
      if (inb) v.x = (unsigned)f2h(a.src0[(size_t)b*a.src0_bs + gy*64 + gx]);
    } else if (inb) {
      v = *reinterpret_cast<const uint4*>(a.cat_in + ((size_t)(b*24 + cp)*4096 + gy*64 + gx)*8);
    }
    AU4[cp*145 + px] = v;
  }
  __syncthreads();

  const int wave = tid >> 6, lane = tid & 63;
  const int n = wave & 1, kg = wave >> 1;        // kg 0..3 (B loaded once/block)
  const int q = lane >> 4, n16 = lane & 15;
  const int row_in = n16 >> 3, col = n16 & 7;
  const int wlo = (n*64 + n16)*32 + q*8;         // lane weight offset (nf adds 512)

  f32x4 zf = {0.f,0.f,0.f,0.f};
  f32x4 acc[4][4];                               // [nf][m]; reused z then x

  // ================= z branch =================
#pragma unroll
  for (int nf = 0; nf < 4; ++nf)
#pragma unroll
    for (int m = 0; m < 4; ++m) acc[nf][m] = zf;

#pragma unroll 1
  for (int u = kg; u < 75; u += 4) {
    int tap = u/3, kc = u - tap*3;
    int ky = tap/5, kx = tap - ky*5;

    f16x8 Bz[4];
#pragma unroll
    for (int nf = 0; nf < 4; ++nf)
      Bz[nf] = *(const f16x8*)(a.wz + (size_t)u*4096 + wlo + nf*512);

    int ai0 = (kc*4 + q)*145 + (row_in + ky)*12 + col + kx;
    f16x8 Ah[4];
#pragma unroll
    for (int m = 0; m < 4; ++m)
      Ah[m] = *(const f16x8*)(AU4 + ai0 + m*24);

#pragma unroll
    for (int nf = 0; nf < 4; ++nf)
#pragma unroll
      for (int m = 0; m < 4; ++m)
        acc[nf][m] = __builtin_amdgcn_mfma_f32_16x16x32_f16(Ah[m], Bz[nf], acc[nf][m], 0,0,0);
  }

  // z-reduce (4-way over kg, f16 exchange): 2 merged passes, 2 outputs/thread
#pragma unroll
  for (int mp = 0; mp < 2; ++mp) {
    __syncthreads();                             // exch free (prev pass read)
#pragma unroll
    for (int ml = 0; ml < 2; ++ml)
#pragma unroll
      for (int nf = 0; nf < 4; ++nf)
        exch[((ml*8 + kg*2 + n)*4 + nf)*64 + lane] =
            __builtin_convertvector(acc[nf][mp*2 + ml], f16x4);
    __syncthreads();
    {
      int ch = tid & 31, p16 = tid >> 5;         // 16 px x 32 ch
#pragma unroll
      for (int ml = 0; ml < 2; ++ml) {
        float g4[4];
#pragma unroll
        for (int g = 0; g < 4; ++g) {
          int co = g*32 + ch;
          int nn = co >> 6, nf = (co >> 4) & 3, nl = co & 15;
          int qq = p16 >> 2;
          f32x4 s = zf;
#pragma unroll
          for (int kgg = 0; kgg < 4; ++kgg)
            s += __builtin_convertvector(
                exch[((ml*8 + kgg*2 + nn)*4 + nf)*64 + qq*16 + nl], f32x4);
          g4[g] = s[p16 & 3] + a.bz[co];
        }
        int m = mp*2 + ml;
        int px = (2*m + (p16 >> 3))*8 + (p16 & 7);
        int pxg = (R0 + (px >> 3))*64 + C0 + (px & 7);
        size_t pix = (size_t)b*4096 + pxg;
        float c = a.cz[pix*32 + ch];
        float cn = sigm(g4[1] + 0.01f)*c + sigm(g4[0])*tanhf(g4[2]);
        float h = sigm(g4[3])*tanhf(cn);
        a.cz[pix*32 + ch] = cn;
        if (a.hz) put_hi(a.hz, b, 64 + ch, pxg, h);
        hbufF[px*68 + 32 + ch] = h;
      }
    }
  }

  // ================= x branch =================
#pragma unroll
  for (int nf = 0; nf < 4; ++nf)
#pragma unroll
    for (int m = 0; m < 4; ++m) acc[nf][m] = zf;

#pragma unroll 1
  for (int xi = kg; xi < 27; xi += 4) {          // halo still live (no overlay)
    int tap3 = xi/3, kc = xi - tap3*3;
    int ky = tap3/3 + 1, kx = tap3 - (ky-1)*3 + 1;

    f16x8 Bx[4];
#pragma unroll
    for (int nf = 0; nf < 4; ++nf)
      Bx[nf] = *(const f16x8*)(a.wx + (size_t)xi*4096 + wlo + nf*512);

    int ai0 = (kc*4 + q)*145 + (row_in + ky)*12 + col + kx;
    f16x8 Ah[4];
#pragma unroll
    for (int m = 0; m < 4; ++m)
      Ah[m] = *(const f16x8*)(AU4 + ai0 + m*24);

#pragma unroll
    for (int nf = 0; nf < 4; ++nf)
#pragma unroll
      for (int m = 0; m < 4; ++m)
        acc[nf][m] = __builtin_amdgcn_mfma_f32_16x16x32_f16(Ah[m], Bx[nf], acc[nf][m], 0,0,0);
  }

  // x-reduce (f16 exchange): 2 merged passes, 2 outputs/thread
#pragma unroll
  for (int mp = 0; mp < 2; ++mp) {
    __syncthreads();
#pragma unroll
    for (int ml = 0; ml < 2; ++ml)
#pragma unroll
      for (int nf = 0; nf < 4; ++nf)
        exch[((ml*8 + kg*2 + n)*4 + nf)*64 + lane] =
            __builtin_convertvector(acc[nf][mp*2 + ml], f16x4);
    __syncthreads();
    {
      int ch = tid & 31, p16 = tid >> 5;
#pragma unroll
      for (int ml = 0; ml < 2; ++ml) {
        float g4[4];
#pragma unroll
        for (int g = 0; g < 4; ++g) {
          int co = g*32 + ch;
          int nn = co >> 6, nf = (co >> 4) & 3, nl = co & 15;
          int qq = p16 >> 2;
          f32x4 s = zf;
#pragma unroll
          for (int kgg = 0; kgg < 4; ++kgg)
            s += __builtin_convertvector(
                exch[((ml*8 + kgg*2 + nn)*4 + nf)*64 + qq*16 + nl], f32x4);
          g4[g] = s[p16 & 3] + a.bx[co];
        }
        int m = mp*2 + ml;
        int px = (2*m + (p16 >> 3))*8 + (p16 & 7);
        int pxg = (R0 + (px >> 3))*64 + C0 + (px & 7);
        size_t pix = (size_t)b*4096 + pxg;
        float c = a.cx_src[pix*32 + ch];
        float cn = sigm(g4[1] + 0.01f)*c + sigm(g4[0])*tanhf(g4[2]);
        float h = sigm(g4[3])*tanhf(cn);
        if (a.cx_dst) a.cx_dst[pix*32 + ch] = cn;
        if (a.hx0) put_hi(a.hx0, b, 32 + ch, pxg, h);
        if (a.hx1) put_hi(a.hx1, b, 32 + ch, pxg, h);
        hbufF[px*68 + ch] = h;
      }
    }
  }
  __syncthreads();

  // ---- phase 3: fused 1x1 y-conv (64 -> 32), scalar (r12 form) ----
  if (a.wy) {
#pragma unroll 1
    for (int it = 0; it < 4; ++it) {
      int idx = tid + it*512;
      int co2 = idx & 31, px = idx >> 5;
      int pxg = (R0 + (px >> 3))*64 + C0 + (px & 7);
      float acc2 = a.by[co2];
#pragma unroll
      for (int c2 = 0; c2 < 64; ++c2) acc2 += a.wy[co2*64 + c2] * hbufF[px*68 + c2];
      if (a.y_dst) put_hi(a.y_dst, b, co2, pxg, acc2);
      if (a.wl) ybufF[px*37 + co2] = acc2;
    }
  }
  // ---- phase 4: fused pred-conv (32 -> 1), last cell only (r12 form) ----
  if (a.wl) {
    __syncthreads();
    if (tid < 64) {
      int px = tid;
      int pxg = (R0 + (px >> 3))*64 + C0 + (px & 7);
      float p = 0.f;
#pragma unroll
      for (int c2 = 0; c2 < 32; ++c2) p += a.wl[c2] * ybufF[px*37 + c2];
      a.pred_out[(size_t)b*4096 + pxg] = p;
      if (a.final_out) a.final_out[(size_t)b*40960 + pxg] = p;
    }
  }
}

extern "C" void kernel_launch(void* const* d_in, const int* in_sizes, int n_in,
                              void* d_out, int out_size, void* d_ws, size_t ws_size,
                              hipStream_t stream)
{
  const float* input_seq = (const float*)d_in[0];
  const float* w_x0 = (const float*)d_in[1];
  const float* b_x0 = (const float*)d_in[2];
  const float* w_z0 = (const float*)d_in[3];
  const float* b_z0 = (const float*)d_in[4];
  const float* w_y0 = (const float*)d_in[5];
  const float* b_y0 = (const float*)d_in[6];
  const float* w_x1 = (const float*)d_in[7];
  const float* b_x1 = (const float*)d_in[8];
  const float* w_z1 = (const float*)d_in[9];
  const float* b_z1 = (const float*)d_in[10];
  const float* w_y1 = (const float*)d_in[11];
  const float* b_y1 = (const float*)d_in[12];
  const float* w_last = (const float*)d_in[13];
  (void)in_sizes; (void)n_in; (void)out_size; (void)ws_size;

  uint8_t* wsb = (uint8_t*)d_ws;
  size_t off = 0;
  auto alloc = [&](size_t bytes) -> void* {
    void* p = wsb + off; off += (bytes + 255) & ~(size_t)255; return p;
  };

  const size_t CATB = (size_t)NB*24*4096*8*2;    // 6,291,456 B (geometry pinned; lo half dead)
  u16* cat[3][3][2];
  for (int l = 0; l < 3; ++l)
    for (int s = 0; s < 3; ++s) {
      cat[l][s][0] = (u16*)alloc(CATB);
      cat[l][s][1] = (s == 0) ? (u16*)alloc(CATB) : cat[l][s][0];
    }
  const size_t CB = (size_t)NB*HW*32*4;          // 2,097,152 B
  float* cx[3][2]; float* cz[3];
  for (int l = 0; l < 3; ++l) { cx[l][0] = (float*)alloc(CB); cx[l][1] = (float*)alloc(CB); }
  for (int l = 0; l < 3; ++l) cz[l] = (float*)alloc(CB);
  size_t zero_bytes = off;                       // cats + cx + cz

  u16 *wzb[9], *wxb[9];
  for (int c = 0; c < 9; ++c) {
    wzb[c] = (u16*)alloc(75*4096*2);             // 25 taps x 3 kc x 128 co x 32 k
    wxb[c] = (u16*)alloc(27*4096*2);             // 9 taps x 3 kc
  }
  float* predbuf = (float*)alloc((size_t)18*NB*HW*4);

  zero4<<<2048, 256, 0, stream>>>((uint4*)wsb, zero_bytes/16);

  for (int l = 0; l < 3; ++l)
    for (int s = 0; s < 3; ++s) {
      int cell = l*3 + s;
      const float *srcx, *srcz; int cin;
      if (l == 0) { srcx = w_x0 + (size_t)s*128*65*9;  srcz = w_z0 + (size_t)s*128*65*25;  cin = 65; }
      else { int li = (l-1)*3 + s;
             srcx = w_x1 + (size_t)li*128*96*9; srcz = w_z1 + (size_t)li*128*96*25; cin = 96; }
      pack_w<<<(75*4096)/256, 256, 0, stream>>>(srcz, wzb[cell], 25, cin, l==0);
      pack_w<<<(27*4096)/256, 256, 0, stream>>>(srcx, wxb[cell], 9, cin, l==0);
    }

  // diagonal wavefront: independent cell groups per step
  static const int diag[5][3] = { {0,-1,-1}, {1,3,-1}, {2,4,6}, {5,7,-1}, {8,-1,-1} };

  for (int step = 0; step < 18; ++step) {
    int par = step & 1, npar = par ^ 1;

    auto make_cell = [&](int l, int s) -> CellArgs {
      CellArgs A;
      A.cat_in = cat[l][s][(s==0) ? par : 0];
      A.src0 = nullptr; A.src0_bs = 0;
      if (l == 0) {
        int j = step + s;
        if (j < 10) { A.src0 = input_seq + (size_t)j*HW; A.src0_bs = 10*HW; }
        else        { A.src0 = predbuf + (size_t)(j-3)*NB*HW; A.src0_bs = HW; }
      }
      int cell = l*3 + s;
      A.wz = wzb[cell]; A.wx = wxb[cell];
      if (l == 0) { A.bx = b_x0 + s*128; A.bz = b_z0 + s*128; }
      else { int li = (l-1)*3 + s; A.bx = b_x1 + li*128; A.bz = b_z1 + li*128; }
      A.cx_src = (s == 2) ? cx[l][1] : cx[l][0];
      A.cx_dst = (s == 0) ? cx[l][0] : ((s == 1) ? cx[l][1] : nullptr);
      A.cz = cz[l];
      A.hx0 = (s == 0) ? cat[l][1][0] : ((s == 1) ? cat[l][2][0] : nullptr);
      A.hx1 = (s == 0) ? cat[l][0][npar] : nullptr;
      A.hz  = (s < 2) ? cat[l][s+1][0] : cat[l][0][npar];
      A.wy = nullptr; A.by = nullptr; A.y_dst = nullptr;
      A.wl = nullptr; A.pred_out = nullptr; A.final_out = nullptr;
      if (l < 2) {
        if (l == 0) { A.wy = w_y0 + (size_t)s*32*64; A.by = b_y0 + s*32; }
        else        { A.wy = w_y1 + (size_t)s*32*64; A.by = b_y1 + s*32; }
        A.y_dst = cat[l+1][s][(s==0) ? par : 0];
      } else if (s == 2) {
        A.wy = w_y1 + (size_t)5*32*64; A.by = b_y1 + 5*32;
        A.wl = w_last;
        A.pred_out = predbuf + (size_t)step*NB*HW;
        A.final_out = (step >= 8) ? ((float*)d_out + (size_t)(step-8)*HW) : nullptr;
      }
      return A;
    };

    for (int d = 0; d < 5; ++d) {
      MultiArgs M{};
      int k = 0;
      for (int j = 0; j < 3; ++j) {
        int cid = diag[d][j];
        if (cid < 0) break;
        M.c[k++] = make_cell(cid/3, cid%3);
      }
      cell_kernel<<<dim3(64, NB, k), 512, 0, stream>>>(M);
    }
  }
}

// Round 12
// 3679.524 us; speedup vs baseline: 1.4624x; 1.1243x over previous
//
#include <hip/hip_runtime.h>
#include <cstddef>
#include <cstdint>

// CubicRNN MI355X — round 16: phase-3 y-conv as MFMA.
// r15 closed the scheduling question (packing ~98%: total = 162 cells x
// 25.5us effective); only per-block work matters. LDS pipe ~73% busy; its
// largest removable item is phase 3's 2048 scalar ds_read_b32 + 2048 global
// wy loads + 2048 FMA wave-insts per block. Replaced by 16 MFMAs:
//   gating stores h as f16 in hbufH[64px][72] (stride 72 = 144B: b128-aligned
//   rows, px -> +4 banks -> 2-way = free);
//   wy pre-packed at init into B-fragments (pack_wy, 4KB/cell) with the
//   K-loop's PROVEN convention (lane&15 = co, lane>>4 = k-quarter);
//   per wave (m = wave>>1, nn = wave&1): 2 x mfma_16x16x32_f16 (kh = x/z
//   half of c2), C-layout col=lane&15=co2, row=(lane>>4)*4+r=px -> put_hi.
// First real numerics change since r7 (y from f16 h, ~5e-4 rel — same order
// as established f16 path); absmax moves off 3.72529e-09, expect ~1e-8.
// Everything else byte-identical to r15. Structure frozen: kg4 x n2
// (B once/block [r10]), sequential z/x (r11), f16 exchange (r12), merged
// reduce passes (r15), folded frame_fill (r12), diagonal z-batching,
// geometry/streams at r4 (r5/r6 lesson). Scalar phase 4 kept (r14 lesson).
// B=4, T=10, C=1, H=W=64, HC=32, S=3, L=3, kx=3, kz=5, ky=1, 18 steps.

typedef __attribute__((ext_vector_type(8))) _Float16 f16x8;
typedef __attribute__((ext_vector_type(4))) _Float16 f16x4;
typedef __attribute__((ext_vector_type(4))) float f32x4;
typedef unsigned short u16;

#define HW 4096
#define NB 4

__device__ __forceinline__ float sigm(float x){ return 1.f/(1.f+expf(-x)); }
__device__ __forceinline__ u16 f2h(float x){
  _Float16 h = (_Float16)x;
  union { _Float16 f; u16 u; } c; c.f = h; return c.u;
}

__global__ __launch_bounds__(256) void zero4(uint4* __restrict__ p, size_t n){
  size_t i = (size_t)blockIdx.x*blockDim.x + threadIdx.x;
  size_t st = (size_t)gridDim.x*blockDim.x;
  uint4 z = make_uint4(0u,0u,0u,0u);
  for (; i < n; i += st) p[i] = z;
}

// Pack conv weights (fp32 OIHW) -> [unit=tap*3+kc][co(128)][k(32)] f16 single,
// cat channels remapped to uniform 96 (layer0: ci0->k0, ci1..64->k32..95).
__global__ __launch_bounds__(256) void pack_w(const float* __restrict__ src,
    u16* __restrict__ dst, int taps, int cin, int l0){
  int idx = blockIdx.x*256 + threadIdx.x;
  int k = idx & 31, co = (idx>>5) & 127, rest = idx >> 12;
  int tap = rest/3, kc = rest - tap*3;
  int p = kc*32 + k;
  int ci = l0 ? ((p==0) ? 0 : ((p>=32) ? p-31 : -1)) : p;
  float wv = 0.f;
  if (ci >= 0 && ci < cin) wv = src[((size_t)co*cin + ci)*taps + tap];
  dst[idx] = f2h(wv);
}

// Pack wy (f32 [32co2][64c2]) into MFMA B-fragments, K-loop convention:
// dst[((nn*2+kh)*64 + lane)*8 + j] = wy[nn*16+(lane&15)][kh*32+(lane>>4)*8+j]
__global__ __launch_bounds__(256) void pack_wy(const float* __restrict__ src,
    u16* __restrict__ dst){
  int idx = blockIdx.x*256 + threadIdx.x;       // 0..2047
  int j = idx & 7, lane = (idx>>3) & 63, kh = (idx>>9) & 1, nn = idx>>10;
  int co2 = nn*16 + (lane & 15);
  int c2  = kh*32 + ((lane>>4)*8) + j;
  dst[idx] = f2h(src[co2*64 + c2]);
}

// cat layout: [b][chunk 0..23][pixel 0..4095][elem 0..7] f16; only chunks
// 0..11 (hi) are live. chunk = slot>>3, elem = slot&7 (slot 0..95).
// Chunks 12..23 are dead padding (address-geometry pinned to r4).
__device__ __forceinline__ void put_hi(u16* base, int b, int slot, int pix, float v){
  size_t o = ((size_t)(b*24 + (slot>>3))*4096 + pix)*8 + (slot&7);
  base[o] = f2h(v);
}

struct CellArgs {
  const u16* cat_in;                       // chunk-planar f16 (12 live chunks)
  const float* src0; int src0_bs;          // l0 frame source (null = use cat plane 0)
  const u16* wz; const u16* wx;            // packed f16 weights
  const u16* wyb;                          // packed wy B-fragments (2048 u16)
  const float *bx, *bz;                    // [128]
  const float* cx_src; float* cx_dst;      // [B][4096][32] fp32 (dst may be null)
  float* cz;                               // in-place
  u16 *hx0, *hx1, *hz, *y_dst;             // cat base pointers (null = skip)
  const float *wy, *by;                    // [32][64],[32]
  const float *wl;                         // [32]; non-null = pred mode
  float *pred_out;                         // predbuf slot [B][4096]
  float *final_out;                        // d_out + ti*4096 (b-stride 40960) or null
};
struct MultiArgs { CellArgs c[3]; };

// LDS map:
//   halo  uint4 [0, 27840)       12 planes x 145
//   exch  f16x4 [27840, 60608)   4096 entries x 8B (2 m-frags x 8 waves x nf4 x 64)
//   hbufH u16   [60608, 69824)   [64px][72] f16 (stride 72 = 144B, b128-aligned)
//   ybufF f32   [27840, 37312)   [64px][37] overlays exch (dead after x-reduce)
// 69,824 B; ~128 unified regs -> 2 blocks/CU, 4 waves/SIMD.
#define LDS_BYTES 69824

__global__ __launch_bounds__(512, 4) void cell_kernel(MultiArgs ma){
  __shared__ __align__(16) char smem[LDS_BYTES];
  uint4* AU4   = (uint4*)smem;
  f16x4* exch  = (f16x4*)(smem + 27840);
  u16*  hbufH  = (u16*)(smem + 60608);
  float* ybufF = (float*)(smem + 27840);

  const CellArgs a = ma.c[blockIdx.z];
  const int tid = threadIdx.x;
  const int b = blockIdx.y;
  const int reg = blockIdx.x;
  const int R0 = (reg >> 3) << 3, C0 = (reg & 7) << 3;   // 8x8 pixel region

  // ---- phase 0: stage 12x12 halo, 12 live chunk-planes, coalesced.
  //      l0 cells: plane 0 built from inseq/predbuf (frame_fill folded). ----
  for (int i = tid; i < 1728; i += 512) {
    int px = i % 144, cp = i / 144;
    int hr = px / 12, hc = px - hr*12;
    int gy = R0 + hr - 2, gx = C0 + hc - 2;
    bool inb = (gy >= 0 && gy < 64 && gx >= 0 && gx < 64);
    uint4 v = make_uint4(0u,0u,0u,0u);
    if (a.src0 && cp == 0) {
      if (inb) v.x = (unsigned)f2h(a.src0[(size_t)b*a.src0_bs + gy*64 + gx]);
    } else if (inb) {
      v = *reinterpret_cast<const uint4*>(a.cat_in + ((size_t)(b*24 + cp)*4096 + gy*64 + gx)*8);
    }
    AU4[cp*145 + px] = v;
  }
  __syncthreads();

  const int wave = tid >> 6, lane = tid & 63;
  const int n = wave & 1, kg = wave >> 1;        // kg 0..3 (B loaded once/block)
  const int q = lane >> 4, n16 = lane & 15;
  const int row_in = n16 >> 3, col = n16 & 7;
  const int wlo = (n*64 + n16)*32 + q*8;         // lane weight offset (nf adds 512)

  f32x4 zf = {0.f,0.f,0.f,0.f};
  f32x4 acc[4][4];                               // [nf][m]; reused z then x

  // ================= z branch =================
#pragma unroll
  for (int nf = 0; nf < 4; ++nf)
#pragma unroll
    for (int m = 0; m < 4; ++m) acc[nf][m] = zf;

#pragma unroll 1
  for (int u = kg; u < 75; u += 4) {
    int tap = u/3, kc = u - tap*3;
    int ky = tap/5, kx = tap - ky*5;

    f16x8 Bz[4];
#pragma unroll
    for (int nf = 0; nf < 4; ++nf)
      Bz[nf] = *(const f16x8*)(a.wz + (size_t)u*4096 + wlo + nf*512);

    int ai0 = (kc*4 + q)*145 + (row_in + ky)*12 + col + kx;
    f16x8 Ah[4];
#pragma unroll
    for (int m = 0; m < 4; ++m)
      Ah[m] = *(const f16x8*)(AU4 + ai0 + m*24);

#pragma unroll
    for (int nf = 0; nf < 4; ++nf)
#pragma unroll
      for (int m = 0; m < 4; ++m)
        acc[nf][m] = __builtin_amdgcn_mfma_f32_16x16x32_f16(Ah[m], Bz[nf], acc[nf][m], 0,0,0);
  }

  // z-reduce (4-way over kg, f16 exchange): 2 merged passes, 2 outputs/thread
#pragma unroll
  for (int mp = 0; mp < 2; ++mp) {
    __syncthreads();                             // exch free (prev pass read)
#pragma unroll
    for (int ml = 0; ml < 2; ++ml)
#pragma unroll
      for (int nf = 0; nf < 4; ++nf)
        exch[((ml*8 + kg*2 + n)*4 + nf)*64 + lane] =
            __builtin_convertvector(acc[nf][mp*2 + ml], f16x4);
    __syncthreads();
    {
      int ch = tid & 31, p16 = tid >> 5;         // 16 px x 32 ch
#pragma unroll
      for (int ml = 0; ml < 2; ++ml) {
        float g4[4];
#pragma unroll
        for (int g = 0; g < 4; ++g) {
          int co = g*32 + ch;
          int nn = co >> 6, nf = (co >> 4) & 3, nl = co & 15;
          int qq = p16 >> 2;
          f32x4 s = zf;
#pragma unroll
          for (int kgg = 0; kgg < 4; ++kgg)
            s += __builtin_convertvector(
                exch[((ml*8 + kgg*2 + nn)*4 + nf)*64 + qq*16 + nl], f32x4);
          g4[g] = s[p16 & 3] + a.bz[co];
        }
        int m = mp*2 + ml;
        int px = (2*m + (p16 >> 3))*8 + (p16 & 7);
        int pxg = (R0 + (px >> 3))*64 + C0 + (px & 7);
        size_t pix = (size_t)b*4096 + pxg;
        float c = a.cz[pix*32 + ch];
        float cn = sigm(g4[1] + 0.01f)*c + sigm(g4[0])*tanhf(g4[2]);
        float h = sigm(g4[3])*tanhf(cn);
        a.cz[pix*32 + ch] = cn;
        if (a.hz) put_hi(a.hz, b, 64 + ch, pxg, h);
        hbufH[px*72 + 32 + ch] = f2h(h);
      }
    }
  }

  // ================= x branch =================
#pragma unroll
  for (int nf = 0; nf < 4; ++nf)
#pragma unroll
    for (int m = 0; m < 4; ++m) acc[nf][m] = zf;

#pragma unroll 1
  for (int xi = kg; xi < 27; xi += 4) {          // halo still live (no overlay)
    int tap3 = xi/3, kc = xi - tap3*3;
    int ky = tap3/3 + 1, kx = tap3 - (ky-1)*3 + 1;

    f16x8 Bx[4];
#pragma unroll
    for (int nf = 0; nf < 4; ++nf)
      Bx[nf] = *(const f16x8*)(a.wx + (size_t)xi*4096 + wlo + nf*512);

    int ai0 = (kc*4 + q)*145 + (row_in + ky)*12 + col + kx;
    f16x8 Ah[4];
#pragma unroll
    for (int m = 0; m < 4; ++m)
      Ah[m] = *(const f16x8*)(AU4 + ai0 + m*24);

#pragma unroll
    for (int nf = 0; nf < 4; ++nf)
#pragma unroll
      for (int m = 0; m < 4; ++m)
        acc[nf][m] = __builtin_amdgcn_mfma_f32_16x16x32_f16(Ah[m], Bx[nf], acc[nf][m], 0,0,0);
  }

  // x-reduce (f16 exchange): 2 merged passes, 2 outputs/thread
#pragma unroll
  for (int mp = 0; mp < 2; ++mp) {
    __syncthreads();
#pragma unroll
    for (int ml = 0; ml < 2; ++ml)
#pragma unroll
      for (int nf = 0; nf < 4; ++nf)
        exch[((ml*8 + kg*2 + n)*4 + nf)*64 + lane] =
            __builtin_convertvector(acc[nf][mp*2 + ml], f16x4);
    __syncthreads();
    {
      int ch = tid & 31, p16 = tid >> 5;
#pragma unroll
      for (int ml = 0; ml < 2; ++ml) {
        float g4[4];
#pragma unroll
        for (int g = 0; g < 4; ++g) {
          int co = g*32 + ch;
          int nn = co >> 6, nf = (co >> 4) & 3, nl = co & 15;
          int qq = p16 >> 2;
          f32x4 s = zf;
#pragma unroll
          for (int kgg = 0; kgg < 4; ++kgg)
            s += __builtin_convertvector(
                exch[((ml*8 + kgg*2 + nn)*4 + nf)*64 + qq*16 + nl], f32x4);
          g4[g] = s[p16 & 3] + a.bx[co];
        }
        int m = mp*2 + ml;
        int px = (2*m + (p16 >> 3))*8 + (p16 & 7);
        int pxg = (R0 + (px >> 3))*64 + C0 + (px & 7);
        size_t pix = (size_t)b*4096 + pxg;
        float c = a.cx_src[pix*32 + ch];
        float cn = sigm(g4[1] + 0.01f)*c + sigm(g4[0])*tanhf(g4[2]);
        float h = sigm(g4[3])*tanhf(cn);
        if (a.cx_dst) a.cx_dst[pix*32 + ch] = cn;
        if (a.hx0) put_hi(a.hx0, b, 32 + ch, pxg, h);
        if (a.hx1) put_hi(a.hx1, b, 32 + ch, pxg, h);
        hbufH[px*72 + ch] = f2h(h);
      }
    }
  }
  __syncthreads();

  // ---- phase 3: fused 1x1 y-conv (64 -> 32) via MFMA, 2 per wave ----
  if (a.wy) {
    const int mfr = wave >> 1, nn = wave & 1;
    f32x4 yacc = zf;
#pragma unroll
    for (int kh = 0; kh < 2; ++kh) {
      f16x8 Af = *(const f16x8*)(hbufH + (mfr*16 + n16)*72 + kh*32 + q*8);
      f16x8 Bf = *(const f16x8*)(a.wyb + (size_t)((nn*2 + kh)*64 + lane)*8);
      yacc = __builtin_amdgcn_mfma_f32_16x16x32_f16(Af, Bf, yacc, 0,0,0);
    }
    int co2 = nn*16 + n16;
    float bb = a.by[co2];
#pragma unroll
    for (int r = 0; r < 4; ++r) {
      int px = mfr*16 + q*4 + r;
      float yv = yacc[r] + bb;
      if (a.y_dst) {
        int pxg = (R0 + (px >> 3))*64 + C0 + (px & 7);
        put_hi(a.y_dst, b, co2, pxg, yv);
      }
      if (a.wl) ybufF[px*37 + co2] = yv;
    }
  }
  // ---- phase 4: fused pred-conv (32 -> 1), last cell only (r12 form) ----
  if (a.wl) {
    __syncthreads();
    if (tid < 64) {
      int px = tid;
      int pxg = (R0 + (px >> 3))*64 + C0 + (px & 7);
      float p = 0.f;
#pragma unroll
      for (int c2 = 0; c2 < 32; ++c2) p += a.wl[c2] * ybufF[px*37 + c2];
      a.pred_out[(size_t)b*4096 + pxg] = p;
      if (a.final_out) a.final_out[(size_t)b*40960 + pxg] = p;
    }
  }
}

extern "C" void kernel_launch(void* const* d_in, const int* in_sizes, int n_in,
                              void* d_out, int out_size, void* d_ws, size_t ws_size,
                              hipStream_t stream)
{
  const float* input_seq = (const float*)d_in[0];
  const float* w_x0 = (const float*)d_in[1];
  const float* b_x0 = (const float*)d_in[2];
  const float* w_z0 = (const float*)d_in[3];
  const float* b_z0 = (const float*)d_in[4];
  const float* w_y0 = (const float*)d_in[5];
  const float* b_y0 = (const float*)d_in[6];
  const float* w_x1 = (const float*)d_in[7];
  const float* b_x1 = (const float*)d_in[8];
  const float* w_z1 = (const float*)d_in[9];
  const float* b_z1 = (const float*)d_in[10];
  const float* w_y1 = (const float*)d_in[11];
  const float* b_y1 = (const float*)d_in[12];
  const float* w_last = (const float*)d_in[13];
  (void)in_sizes; (void)n_in; (void)out_size; (void)ws_size;

  uint8_t* wsb = (uint8_t*)d_ws;
  size_t off = 0;
  auto alloc = [&](size_t bytes) -> void* {
    void* p = wsb + off; off += (bytes + 255) & ~(size_t)255; return p;
  };

  const size_t CATB = (size_t)NB*24*4096*8*2;    // 6,291,456 B (geometry pinned; lo half dead)
  u16* cat[3][3][2];
  for (int l = 0; l < 3; ++l)
    for (int s = 0; s < 3; ++s) {
      cat[l][s][0] = (u16*)alloc(CATB);
      cat[l][s][1] = (s == 0) ? (u16*)alloc(CATB) : cat[l][s][0];
    }
  const size_t CB = (size_t)NB*HW*32*4;          // 2,097,152 B
  float* cx[3][2]; float* cz[3];
  for (int l = 0; l < 3; ++l) { cx[l][0] = (float*)alloc(CB); cx[l][1] = (float*)alloc(CB); }
  for (int l = 0; l < 3; ++l) cz[l] = (float*)alloc(CB);
  size_t zero_bytes = off;                       // cats + cx + cz

  u16 *wzb[9], *wxb[9], *wyf[9];
  for (int c = 0; c < 9; ++c) {
    wzb[c] = (u16*)alloc(75*4096*2);             // 25 taps x 3 kc x 128 co x 32 k
    wxb[c] = (u16*)alloc(27*4096*2);             // 9 taps x 3 kc
    wyf[c] = (u16*)alloc(2048*2);                // wy B-fragments
  }
  float* predbuf = (float*)alloc((size_t)18*NB*HW*4);

  zero4<<<2048, 256, 0, stream>>>((uint4*)wsb, zero_bytes/16);

  for (int l = 0; l < 3; ++l)
    for (int s = 0; s < 3; ++s) {
      int cell = l*3 + s;
      const float *srcx, *srcz; int cin;
      if (l == 0) { srcx = w_x0 + (size_t)s*128*65*9;  srcz = w_z0 + (size_t)s*128*65*25;  cin = 65; }
      else { int li = (l-1)*3 + s;
             srcx = w_x1 + (size_t)li*128*96*9; srcz = w_z1 + (size_t)li*128*96*25; cin = 96; }
      pack_w<<<(75*4096)/256, 256, 0, stream>>>(srcz, wzb[cell], 25, cin, l==0);
      pack_w<<<(27*4096)/256, 256, 0, stream>>>(srcx, wxb[cell], 9, cin, l==0);
      // pack wy fragments for cells that have a y-conv
      const float* wysrc = nullptr;
      if (l == 0) wysrc = w_y0 + (size_t)s*32*64;
      else if (l == 1) wysrc = w_y1 + (size_t)s*32*64;
      else if (s == 2) wysrc = w_y1 + (size_t)5*32*64;
      if (wysrc) pack_wy<<<8, 256, 0, stream>>>(wysrc, wyf[cell]);
    }

  // diagonal wavefront: independent cell groups per step
  static const int diag[5][3] = { {0,-1,-1}, {1,3,-1}, {2,4,6}, {5,7,-1}, {8,-1,-1} };

  for (int step = 0; step < 18; ++step) {
    int par = step & 1, npar = par ^ 1;

    auto make_cell = [&](int l, int s) -> CellArgs {
      CellArgs A;
      A.cat_in = cat[l][s][(s==0) ? par : 0];
      A.src0 = nullptr; A.src0_bs = 0;
      if (l == 0) {
        int j = step + s;
        if (j < 10) { A.src0 = input_seq + (size_t)j*HW; A.src0_bs = 10*HW; }
        else        { A.src0 = predbuf + (size_t)(j-3)*NB*HW; A.src0_bs = HW; }
      }
      int cell = l*3 + s;
      A.wz = wzb[cell]; A.wx = wxb[cell]; A.wyb = wyf[cell];
      if (l == 0) { A.bx = b_x0 + s*128; A.bz = b_z0 + s*128; }
      else { int li = (l-1)*3 + s; A.bx = b_x1 + li*128; A.bz = b_z1 + li*128; }
      A.cx_src = (s == 2) ? cx[l][1] : cx[l][0];
      A.cx_dst = (s == 0) ? cx[l][0] : ((s == 1) ? cx[l][1] : nullptr);
      A.cz = cz[l];
      A.hx0 = (s == 0) ? cat[l][1][0] : ((s == 1) ? cat[l][2][0] : nullptr);
      A.hx1 = (s == 0) ? cat[l][0][npar] : nullptr;
      A.hz  = (s < 2) ? cat[l][s+1][0] : cat[l][0][npar];
      A.wy = nullptr; A.by = nullptr; A.y_dst = nullptr;
      A.wl = nullptr; A.pred_out = nullptr; A.final_out = nullptr;
      if (l < 2) {
        if (l == 0) { A.wy = w_y0 + (size_t)s*32*64; A.by = b_y0 + s*32; }
        else        { A.wy = w_y1 + (size_t)s*32*64; A.by = b_y1 + s*32; }
        A.y_dst = cat[l+1][s][(s==0) ? par : 0];
      } else if (s == 2) {
        A.wy = w_y1 + (size_t)5*32*64; A.by = b_y1 + 5*32;
        A.wl = w_last;
        A.pred_out = predbuf + (size_t)step*NB*HW;
        A.final_out = (step >= 8) ? ((float*)d_out + (size_t)(step-8)*HW) : nullptr;
      }
      return A;
    };

    for (int d = 0; d < 5; ++d) {
      MultiArgs M{};
      int k = 0;
      for (int j = 0; j < 3; ++j) {
        int cid = diag[d][j];
        if (cid < 0) break;
        M.c[k++] = make_cell(cid/3, cid%3);
      }
      cell_kernel<<<dim3(64, NB, k), 512, 0, stream>>>(M);
    }
  }
}

// Round 13
// 3476.122 us; speedup vs baseline: 1.5480x; 1.0585x over previous
//
#include <hip/hip_runtime.h>
#include <cstddef>
#include <cstdint>

// CubicRNN MI355X — round 17: fast gate math, isolated, on the r16 base.
// r16 re-attribution: r12=78.8 (libcall,scalar) r14=99.8 (libcall,vec)
// r13=93.6 (fastmath,vec) -> the vec rewrite cost +21us; fastmath ON TOP
// was -6.2us. r13's post-mortem blamed the wrong component. This round
// tests fastmath alone: sigm = v_rcp(1+v_exp), tanh via e^{2|x|}
// (overflow-graceful), ~27 VALU insts vs ~98 libcall per output.
// Transcendentals are ~2/3 of the 35% VALUBusy (top pipe). Everything
// else byte-identical to r16. r13 evidence: absmax stays 3.72529e-09.
// Structure frozen: kg4 x n2 (B once/block [r10]), sequential z/x (r11),
// f16 exchange (r12), merged reduce (r15), MFMA y-conv (r16), folded
// frame_fill (r12), diagonal z-batching, geometry/streams at r4 (r5/r6).
// B=4, T=10, C=1, H=W=64, HC=32, S=3, L=3, kx=3, kz=5, ky=1, 18 steps.

typedef __attribute__((ext_vector_type(8))) _Float16 f16x8;
typedef __attribute__((ext_vector_type(4))) _Float16 f16x4;
typedef __attribute__((ext_vector_type(4))) float f32x4;
typedef unsigned short u16;

#define HW 4096
#define NB 4

__device__ __forceinline__ float sigm(float x){
  return __builtin_amdgcn_rcpf(1.f + __expf(-x));
}
__device__ __forceinline__ float tanh_f(float x){
  float e = __expf(2.f*fabsf(x));                // inf for large |x| -> t=1 (ok)
  float t = 1.f - 2.f*__builtin_amdgcn_rcpf(e + 1.f);
  return copysignf(t, x);
}
__device__ __forceinline__ u16 f2h(float x){
  _Float16 h = (_Float16)x;
  union { _Float16 f; u16 u; } c; c.f = h; return c.u;
}

__global__ __launch_bounds__(256) void zero4(uint4* __restrict__ p, size_t n){
  size_t i = (size_t)blockIdx.x*blockDim.x + threadIdx.x;
  size_t st = (size_t)gridDim.x*blockDim.x;
  uint4 z = make_uint4(0u,0u,0u,0u);
  for (; i < n; i += st) p[i] = z;
}

// Pack conv weights (fp32 OIHW) -> [unit=tap*3+kc][co(128)][k(32)] f16 single,
// cat channels remapped to uniform 96 (layer0: ci0->k0, ci1..64->k32..95).
__global__ __launch_bounds__(256) void pack_w(const float* __restrict__ src,
    u16* __restrict__ dst, int taps, int cin, int l0){
  int idx = blockIdx.x*256 + threadIdx.x;
  int k = idx & 31, co = (idx>>5) & 127, rest = idx >> 12;
  int tap = rest/3, kc = rest - tap*3;
  int p = kc*32 + k;
  int ci = l0 ? ((p==0) ? 0 : ((p>=32) ? p-31 : -1)) : p;
  float wv = 0.f;
  if (ci >= 0 && ci < cin) wv = src[((size_t)co*cin + ci)*taps + tap];
  dst[idx] = f2h(wv);
}

// Pack wy (f32 [32co2][64c2]) into MFMA B-fragments, K-loop convention:
// dst[((nn*2+kh)*64 + lane)*8 + j] = wy[nn*16+(lane&15)][kh*32+(lane>>4)*8+j]
__global__ __launch_bounds__(256) void pack_wy(const float* __restrict__ src,
    u16* __restrict__ dst){
  int idx = blockIdx.x*256 + threadIdx.x;       // 0..2047
  int j = idx & 7, lane = (idx>>3) & 63, kh = (idx>>9) & 1, nn = idx>>10;
  int co2 = nn*16 + (lane & 15);
  int c2  = kh*32 + ((lane>>4)*8) + j;
  dst[idx] = f2h(src[co2*64 + c2]);
}

// cat layout: [b][chunk 0..23][pixel 0..4095][elem 0..7] f16; only chunks
// 0..11 (hi) are live. chunk = slot>>3, elem = slot&7 (slot 0..95).
// Chunks 12..23 are dead padding (address-geometry pinned to r4).
__device__ __forceinline__ void put_hi(u16* base, int b, int slot, int pix, float v){
  size_t o = ((size_t)(b*24 + (slot>>3))*4096 + pix)*8 + (slot&7);
  base[o] = f2h(v);
}

struct CellArgs {
  const u16* cat_in;                       // chunk-planar f16 (12 live chunks)
  const float* src0; int src0_bs;          // l0 frame source (null = use cat plane 0)
  const u16* wz; const u16* wx;            // packed f16 weights
  const u16* wyb;                          // packed wy B-fragments (2048 u16)
  const float *bx, *bz;                    // [128]
  const float* cx_src; float* cx_dst;      // [B][4096][32] fp32 (dst may be null)
  float* cz;                               // in-place
  u16 *hx0, *hx1, *hz, *y_dst;             // cat base pointers (null = skip)
  const float *wy, *by;                    // [32][64],[32]
  const float *wl;                         // [32]; non-null = pred mode
  float *pred_out;                         // predbuf slot [B][4096]
  float *final_out;                        // d_out + ti*4096 (b-stride 40960) or null
};
struct MultiArgs { CellArgs c[3]; };

// LDS map:
//   halo  uint4 [0, 27840)       12 planes x 145
//   exch  f16x4 [27840, 60608)   4096 entries x 8B (2 m-frags x 8 waves x nf4 x 64)
//   hbufH u16   [60608, 69824)   [64px][72] f16 (stride 72 = 144B, b128-aligned)
//   ybufF f32   [27840, 37312)   [64px][37] overlays exch (dead after x-reduce)
// 69,824 B; ~128 unified regs -> 2 blocks/CU, 4 waves/SIMD.
#define LDS_BYTES 69824

__global__ __launch_bounds__(512, 4) void cell_kernel(MultiArgs ma){
  __shared__ __align__(16) char smem[LDS_BYTES];
  uint4* AU4   = (uint4*)smem;
  f16x4* exch  = (f16x4*)(smem + 27840);
  u16*  hbufH  = (u16*)(smem + 60608);
  float* ybufF = (float*)(smem + 27840);

  const CellArgs a = ma.c[blockIdx.z];
  const int tid = threadIdx.x;
  const int b = blockIdx.y;
  const int reg = blockIdx.x;
  const int R0 = (reg >> 3) << 3, C0 = (reg & 7) << 3;   // 8x8 pixel region

  // ---- phase 0: stage 12x12 halo, 12 live chunk-planes, coalesced.
  //      l0 cells: plane 0 built from inseq/predbuf (frame_fill folded). ----
  for (int i = tid; i < 1728; i += 512) {
    int px = i % 144, cp = i / 144;
    int hr = px / 12, hc = px - hr*12;
    int gy = R0 + hr - 2, gx = C0 + hc - 2;
    bool inb = (gy >= 0 && gy < 64 && gx >= 0 && gx < 64);
    uint4 v = make_uint4(0u,0u,0u,0u);
    if (a.src0 && cp == 0) {
      if (inb) v.x = (unsigned)f2h(a.src0[(size_t)b*a.src0_bs + gy*64 + gx]);
    } else if (inb) {
      v = *reinterpret_cast<const uint4*>(a.cat_in + ((size_t)(b*24 + cp)*4096 + gy*64 + gx)*8);
    }
    AU4[cp*145 + px] = v;
  }
  __syncthreads();

  const int wave = tid >> 6, lane = tid & 63;
  const int n = wave & 1, kg = wave >> 1;        // kg 0..3 (B loaded once/block)
  const int q = lane >> 4, n16 = lane & 15;
  const int row_in = n16 >> 3, col = n16 & 7;
  const int wlo = (n*64 + n16)*32 + q*8;         // lane weight offset (nf adds 512)

  f32x4 zf = {0.f,0.f,0.f,0.f};
  f32x4 acc[4][4];                               // [nf][m]; reused z then x

  // ================= z branch =================
#pragma unroll
  for (int nf = 0; nf < 4; ++nf)
#pragma unroll
    for (int m = 0; m < 4; ++m) acc[nf][m] = zf;

#pragma unroll 1
  for (int u = kg; u < 75; u += 4) {
    int tap = u/3, kc = u - tap*3;
    int ky = tap/5, kx = tap - ky*5;

    f16x8 Bz[4];
#pragma unroll
    for (int nf = 0; nf < 4; ++nf)
      Bz[nf] = *(const f16x8*)(a.wz + (size_t)u*4096 + wlo + nf*512);

    int ai0 = (kc*4 + q)*145 + (row_in + ky)*12 + col + kx;
    f16x8 Ah[4];
#pragma unroll
    for (int m = 0; m < 4; ++m)
      Ah[m] = *(const f16x8*)(AU4 + ai0 + m*24);

#pragma unroll
    for (int nf = 0; nf < 4; ++nf)
#pragma unroll
      for (int m = 0; m < 4; ++m)
        acc[nf][m] = __builtin_amdgcn_mfma_f32_16x16x32_f16(Ah[m], Bz[nf], acc[nf][m], 0,0,0);
  }

  // z-reduce (4-way over kg, f16 exchange): 2 merged passes, 2 outputs/thread
#pragma unroll
  for (int mp = 0; mp < 2; ++mp) {
    __syncthreads();                             // exch free (prev pass read)
#pragma unroll
    for (int ml = 0; ml < 2; ++ml)
#pragma unroll
      for (int nf = 0; nf < 4; ++nf)
        exch[((ml*8 + kg*2 + n)*4 + nf)*64 + lane] =
            __builtin_convertvector(acc[nf][mp*2 + ml], f16x4);
    __syncthreads();
    {
      int ch = tid & 31, p16 = tid >> 5;         // 16 px x 32 ch
#pragma unroll
      for (int ml = 0; ml < 2; ++ml) {
        float g4[4];
#pragma unroll
        for (int g = 0; g < 4; ++g) {
          int co = g*32 + ch;
          int nn = co >> 6, nf = (co >> 4) & 3, nl = co & 15;
          int qq = p16 >> 2;
          f32x4 s = zf;
#pragma unroll
          for (int kgg = 0; kgg < 4; ++kgg)
            s += __builtin_convertvector(
                exch[((ml*8 + kgg*2 + nn)*4 + nf)*64 + qq*16 + nl], f32x4);
          g4[g] = s[p16 & 3] + a.bz[co];
        }
        int m = mp*2 + ml;
        int px = (2*m + (p16 >> 3))*8 + (p16 & 7);
        int pxg = (R0 + (px >> 3))*64 + C0 + (px & 7);
        size_t pix = (size_t)b*4096 + pxg;
        float c = a.cz[pix*32 + ch];
        float cn = sigm(g4[1] + 0.01f)*c + sigm(g4[0])*tanh_f(g4[2]);
        float h = sigm(g4[3])*tanh_f(cn);
        a.cz[pix*32 + ch] = cn;
        if (a.hz) put_hi(a.hz, b, 64 + ch, pxg, h);
        hbufH[px*72 + 32 + ch] = f2h(h);
      }
    }
  }

  // ================= x branch =================
#pragma unroll
  for (int nf = 0; nf < 4; ++nf)
#pragma unroll
    for (int m = 0; m < 4; ++m) acc[nf][m] = zf;

#pragma unroll 1
  for (int xi = kg; xi < 27; xi += 4) {          // halo still live (no overlay)
    int tap3 = xi/3, kc = xi - tap3*3;
    int ky = tap3/3 + 1, kx = tap3 - (ky-1)*3 + 1;

    f16x8 Bx[4];
#pragma unroll
    for (int nf = 0; nf < 4; ++nf)
      Bx[nf] = *(const f16x8*)(a.wx + (size_t)xi*4096 + wlo + nf*512);

    int ai0 = (kc*4 + q)*145 + (row_in + ky)*12 + col + kx;
    f16x8 Ah[4];
#pragma unroll
    for (int m = 0; m < 4; ++m)
      Ah[m] = *(const f16x8*)(AU4 + ai0 + m*24);

#pragma unroll
    for (int nf = 0; nf < 4; ++nf)
#pragma unroll
      for (int m = 0; m < 4; ++m)
        acc[nf][m] = __builtin_amdgcn_mfma_f32_16x16x32_f16(Ah[m], Bx[nf], acc[nf][m], 0,0,0);
  }

  // x-reduce (f16 exchange): 2 merged passes, 2 outputs/thread
#pragma unroll
  for (int mp = 0; mp < 2; ++mp) {
    __syncthreads();
#pragma unroll
    for (int ml = 0; ml < 2; ++ml)
#pragma unroll
      for (int nf = 0; nf < 4; ++nf)
        exch[((ml*8 + kg*2 + n)*4 + nf)*64 + lane] =
            __builtin_convertvector(acc[nf][mp*2 + ml], f16x4);
    __syncthreads();
    {
      int ch = tid & 31, p16 = tid >> 5;
#pragma unroll
      for (int ml = 0; ml < 2; ++ml) {
        float g4[4];
#pragma unroll
        for (int g = 0; g < 4; ++g) {
          int co = g*32 + ch;
          int nn = co >> 6, nf = (co >> 4) & 3, nl = co & 15;
          int qq = p16 >> 2;
          f32x4 s = zf;
#pragma unroll
          for (int kgg = 0; kgg < 4; ++kgg)
            s += __builtin_convertvector(
                exch[((ml*8 + kgg*2 + nn)*4 + nf)*64 + qq*16 + nl], f32x4);
          g4[g] = s[p16 & 3] + a.bx[co];
        }
        int m = mp*2 + ml;
        int px = (2*m + (p16 >> 3))*8 + (p16 & 7);
        int pxg = (R0 + (px >> 3))*64 + C0 + (px & 7);
        size_t pix = (size_t)b*4096 + pxg;
        float c = a.cx_src[pix*32 + ch];
        float cn = sigm(g4[1] + 0.01f)*c + sigm(g4[0])*tanh_f(g4[2]);
        float h = sigm(g4[3])*tanh_f(cn);
        if (a.cx_dst) a.cx_dst[pix*32 + ch] = cn;
        if (a.hx0) put_hi(a.hx0, b, 32 + ch, pxg, h);
        if (a.hx1) put_hi(a.hx1, b, 32 + ch, pxg, h);
        hbufH[px*72 + ch] = f2h(h);
      }
    }
  }
  __syncthreads();

  // ---- phase 3: fused 1x1 y-conv (64 -> 32) via MFMA, 2 per wave ----
  if (a.wy) {
    const int mfr = wave >> 1, nn = wave & 1;
    f32x4 yacc = zf;
#pragma unroll
    for (int kh = 0; kh < 2; ++kh) {
      f16x8 Af = *(const f16x8*)(hbufH + (mfr*16 + n16)*72 + kh*32 + q*8);
      f16x8 Bf = *(const f16x8*)(a.wyb + (size_t)((nn*2 + kh)*64 + lane)*8);
      yacc = __builtin_amdgcn_mfma_f32_16x16x32_f16(Af, Bf, yacc, 0,0,0);
    }
    int co2 = nn*16 + n16;
    float bb = a.by[co2];
#pragma unroll
    for (int r = 0; r < 4; ++r) {
      int px = mfr*16 + q*4 + r;
      float yv = yacc[r] + bb;
      if (a.y_dst) {
        int pxg = (R0 + (px >> 3))*64 + C0 + (px & 7);
        put_hi(a.y_dst, b, co2, pxg, yv);
      }
      if (a.wl) ybufF[px*37 + co2] = yv;
    }
  }
  // ---- phase 4: fused pred-conv (32 -> 1), last cell only (r12 form) ----
  if (a.wl) {
    __syncthreads();
    if (tid < 64) {
      int px = tid;
      int pxg = (R0 + (px >> 3))*64 + C0 + (px & 7);
      float p = 0.f;
#pragma unroll
      for (int c2 = 0; c2 < 32; ++c2) p += a.wl[c2] * ybufF[px*37 + c2];
      a.pred_out[(size_t)b*4096 + pxg] = p;
      if (a.final_out) a.final_out[(size_t)b*40960 + pxg] = p;
    }
  }
}

extern "C" void kernel_launch(void* const* d_in, const int* in_sizes, int n_in,
                              void* d_out, int out_size, void* d_ws, size_t ws_size,
                              hipStream_t stream)
{
  const float* input_seq = (const float*)d_in[0];
  const float* w_x0 = (const float*)d_in[1];
  const float* b_x0 = (const float*)d_in[2];
  const float* w_z0 = (const float*)d_in[3];
  const float* b_z0 = (const float*)d_in[4];
  const float* w_y0 = (const float*)d_in[5];
  const float* b_y0 = (const float*)d_in[6];
  const float* w_x1 = (const float*)d_in[7];
  const float* b_x1 = (const float*)d_in[8];
  const float* w_z1 = (const float*)d_in[9];
  const float* b_z1 = (const float*)d_in[10];
  const float* w_y1 = (const float*)d_in[11];
  const float* b_y1 = (const float*)d_in[12];
  const float* w_last = (const float*)d_in[13];
  (void)in_sizes; (void)n_in; (void)out_size; (void)ws_size;

  uint8_t* wsb = (uint8_t*)d_ws;
  size_t off = 0;
  auto alloc = [&](size_t bytes) -> void* {
    void* p = wsb + off; off += (bytes + 255) & ~(size_t)255; return p;
  };

  const size_t CATB = (size_t)NB*24*4096*8*2;    // 6,291,456 B (geometry pinned; lo half dead)
  u16* cat[3][3][2];
  for (int l = 0; l < 3; ++l)
    for (int s = 0; s < 3; ++s) {
      cat[l][s][0] = (u16*)alloc(CATB);
      cat[l][s][1] = (s == 0) ? (u16*)alloc(CATB) : cat[l][s][0];
    }
  const size_t CB = (size_t)NB*HW*32*4;          // 2,097,152 B
  float* cx[3][2]; float* cz[3];
  for (int l = 0; l < 3; ++l) { cx[l][0] = (float*)alloc(CB); cx[l][1] = (float*)alloc(CB); }
  for (int l = 0; l < 3; ++l) cz[l] = (float*)alloc(CB);
  size_t zero_bytes = off;                       // cats + cx + cz

  u16 *wzb[9], *wxb[9], *wyf[9];
  for (int c = 0; c < 9; ++c) {
    wzb[c] = (u16*)alloc(75*4096*2);             // 25 taps x 3 kc x 128 co x 32 k
    wxb[c] = (u16*)alloc(27*4096*2);             // 9 taps x 3 kc
    wyf[c] = (u16*)alloc(2048*2);                // wy B-fragments
  }
  float* predbuf = (float*)alloc((size_t)18*NB*HW*4);

  zero4<<<2048, 256, 0, stream>>>((uint4*)wsb, zero_bytes/16);

  for (int l = 0; l < 3; ++l)
    for (int s = 0; s < 3; ++s) {
      int cell = l*3 + s;
      const float *srcx, *srcz; int cin;
      if (l == 0) { srcx = w_x0 + (size_t)s*128*65*9;  srcz = w_z0 + (size_t)s*128*65*25;  cin = 65; }
      else { int li = (l-1)*3 + s;
             srcx = w_x1 + (size_t)li*128*96*9; srcz = w_z1 + (size_t)li*128*96*25; cin = 96; }
      pack_w<<<(75*4096)/256, 256, 0, stream>>>(srcz, wzb[cell], 25, cin, l==0);
      pack_w<<<(27*4096)/256, 256, 0, stream>>>(srcx, wxb[cell], 9, cin, l==0);
      // pack wy fragments for cells that have a y-conv
      const float* wysrc = nullptr;
      if (l == 0) wysrc = w_y0 + (size_t)s*32*64;
      else if (l == 1) wysrc = w_y1 + (size_t)s*32*64;
      else if (s == 2) wysrc = w_y1 + (size_t)5*32*64;
      if (wysrc) pack_wy<<<8, 256, 0, stream>>>(wysrc, wyf[cell]);
    }

  // diagonal wavefront: independent cell groups per step
  static const int diag[5][3] = { {0,-1,-1}, {1,3,-1}, {2,4,6}, {5,7,-1}, {8,-1,-1} };

  for (int step = 0; step < 18; ++step) {
    int par = step & 1, npar = par ^ 1;

    auto make_cell = [&](int l, int s) -> CellArgs {
      CellArgs A;
      A.cat_in = cat[l][s][(s==0) ? par : 0];
      A.src0 = nullptr; A.src0_bs = 0;
      if (l == 0) {
        int j = step + s;
        if (j < 10) { A.src0 = input_seq + (size_t)j*HW; A.src0_bs = 10*HW; }
        else        { A.src0 = predbuf + (size_t)(j-3)*NB*HW; A.src0_bs = HW; }
      }
      int cell = l*3 + s;
      A.wz = wzb[cell]; A.wx = wxb[cell]; A.wyb = wyf[cell];
      if (l == 0) { A.bx = b_x0 + s*128; A.bz = b_z0 + s*128; }
      else { int li = (l-1)*3 + s; A.bx = b_x1 + li*128; A.bz = b_z1 + li*128; }
      A.cx_src = (s == 2) ? cx[l][1] : cx[l][0];
      A.cx_dst = (s == 0) ? cx[l][0] : ((s == 1) ? cx[l][1] : nullptr);
      A.cz = cz[l];
      A.hx0 = (s == 0) ? cat[l][1][0] : ((s == 1) ? cat[l][2][0] : nullptr);
      A.hx1 = (s == 0) ? cat[l][0][npar] : nullptr;
      A.hz  = (s < 2) ? cat[l][s+1][0] : cat[l][0][npar];
      A.wy = nullptr; A.by = nullptr; A.y_dst = nullptr;
      A.wl = nullptr; A.pred_out = nullptr; A.final_out = nullptr;
      if (l < 2) {
        if (l == 0) { A.wy = w_y0 + (size_t)s*32*64; A.by = b_y0 + s*32; }
        else        { A.wy = w_y1 + (size_t)s*32*64; A.by = b_y1 + s*32; }
        A.y_dst = cat[l+1][s][(s==0) ? par : 0];
      } else if (s == 2) {
        A.wy = w_y1 + (size_t)5*32*64; A.by = b_y1 + 5*32;
        A.wl = w_last;
        A.pred_out = predbuf + (size_t)step*NB*HW;
        A.final_out = (step >= 8) ? ((float*)d_out + (size_t)(step-8)*HW) : nullptr;
      }
      return A;
    };

    for (int d = 0; d < 5; ++d) {
      MultiArgs M{};
      int k = 0;
      for (int j = 0; j < 3; ++j) {
        int cid = diag[d][j];
        if (cid < 0) break;
        M.c[k++] = make_cell(cid/3, cid%3);
      }
      cell_kernel<<<dim3(64, NB, k), 512, 0, stream>>>(M);
    }
  }
}